// Round 5
// baseline (236.582 us; speedup 1.0000x reference)
//
#include <hip/hip_runtime.h>
#include <hip/hip_bf16.h>

// Problem constants: B=4, L=2048, H=8, D=64, SAMPLE_K=N_TOP=40
#define BB 4
#define LL 2048
#define HH 8
#define DD 64
#define SK 40
#define NT 40
#define CH 256              // keys per attn chunk
#define NCH (LL / CH)       // 8 chunks per (b,h)
#define QH 20               // queries per attn block (40 split in 2)

// ---------------------------------------------------------------------------
// Kernel 1: M[bh][l] = max_s(q . k_{idx[l,s]}) - (sum_s q . k_{idx[l,s]}) / L
// One block (256 thr) per (b,l); all 8 heads together; 2-KB coalesced gathers.
// XCD swizzle: xcd = blk&7 serves one b (2 XCDs per b) so each XCD's L2 (4 MB)
// holds exactly its K[b] slice (4 MB) -> gather hits L2.
// ---------------------------------------------------------------------------
__global__ __launch_bounds__(256) void compute_m_kernel(
        const float* __restrict__ Q, const float* __restrict__ K,
        const int* __restrict__ idx, float* __restrict__ M) {
    __shared__ int sidx[SK];
    int blk = blockIdx.x;
    int x = blk & 7, g = blk >> 3;
    int b = x >> 1;                    // XCD pair -> batch
    int l = (g << 1) | (x & 1);
    int t = threadIdx.x;
    int h = t >> 5, j = t & 31;

    if (t < SK) sidx[t] = idx[(size_t)l * SK + t];

    const float2* Q2 = (const float2*)Q + ((size_t)b * LL + l) * 256;
    float2 qv = Q2[t];

    const float2* K2 = (const float2*)K + (size_t)b * LL * 256;
    __syncthreads();

    float mx = -INFINITY;
    float sm = 0.0f;
    #pragma unroll 8
    for (int s = 0; s < SK; ++s) {
        int kk = sidx[s];
        float2 kv = K2[(size_t)kk * 256 + t];
        float p = qv.x * kv.x + qv.y * kv.y;
        #pragma unroll
        for (int off = 16; off >= 1; off >>= 1)
            p += __shfl_xor(p, off, 64);
        mx = fmaxf(mx, p);
        sm += p;
    }
    if (j == 0)
        M[((size_t)b * HH + h) * LL + l] = mx - sm * (1.0f / (float)LL);
}

// ---------------------------------------------------------------------------
// Kernel 2: top-40 per (b,h), lower index wins ties.
// Packed key: (ordered_float << 11) | (2047 - i). Incremental argmax: each
// thread keeps its 8-slot max in a register; only the extracted winner's
// owner rescans its slots per round.
// ---------------------------------------------------------------------------
__global__ __launch_bounds__(256) void topk_kernel(const float* __restrict__ M,
                                                   int* __restrict__ topi) {
    __shared__ unsigned long long keys[LL];   // 16 KB
    __shared__ unsigned long long wmax[4];
    __shared__ int win;
    int bh = blockIdx.x;
    int t  = threadIdx.x;
    int lane = t & 63, w = t >> 6;

    unsigned long long kmax = 0ULL;
    #pragma unroll
    for (int j = 0; j < 8; ++j) {
        int i = t + 256 * j;
        unsigned int bits = __float_as_uint(M[(size_t)bh * LL + i]);
        bits = (bits & 0x80000000u) ? ~bits : (bits | 0x80000000u);
        unsigned long long k = ((unsigned long long)bits << 11)
                             | (unsigned int)(LL - 1 - i);
        keys[i] = k;
        if (k > kmax) kmax = k;
    }
    __syncthreads();

    for (int u = 0; u < NT; ++u) {
        unsigned long long k = kmax;
        #pragma unroll
        for (int off = 32; off >= 1; off >>= 1) {
            unsigned long long o = __shfl_xor(k, off, 64);
            if (o > k) k = o;
        }
        if (lane == 0) wmax[w] = k;
        __syncthreads();
        if (t == 0) {
            unsigned long long k0 = wmax[0], k1 = wmax[1], k2 = wmax[2], k3 = wmax[3];
            if (k1 > k0) k0 = k1;
            if (k3 > k2) k2 = k3;
            if (k2 > k0) k0 = k2;
            int i = (LL - 1) - (int)(k0 & 0x7FF);
            topi[bh * NT + u] = i;
            keys[i] = 0ULL;
            win = i;
        }
        __syncthreads();
        if ((win & 255) == t) {          // only the owner rescans
            kmax = 0ULL;
            #pragma unroll
            for (int j = 0; j < 8; ++j) {
                unsigned long long kk = keys[t + 256 * j];
                if (kk > kmax) kmax = kk;
            }
        }
    }
}

// ---------------------------------------------------------------------------
// Kernel 3: flash-chunked attention, query-split for 2 waves/SIMD.
// Block = (qhalf, b,h, chunk of 256 keys); 4 waves; wave owns 64 keys
// (K row in 16 float4 regs, V col in 64 regs) and processes 20 queries.
// qhalf = blk>>8 so both halves of a chunk land on the same XCD (256%8==0).
// ---------------------------------------------------------------------------
__global__ __launch_bounds__(256) void attn_kernel(
        const float* __restrict__ Q, const float* __restrict__ K,
        const float* __restrict__ V, const int* __restrict__ topi,
        float* __restrict__ pm, float* __restrict__ pl, float* __restrict__ po) {
    __shared__ float  qs[QH][DD];        //  5120 B
    __shared__ float4 e4buf[4][64];      //  4096 B
    __shared__ float  oarea[4][QH][DD];  // 20480 B
    __shared__ float  mlarea[4][QH][2];  //   640 B

    int blk = blockIdx.x;
    int qh  = blk >> 8;                  // 0/1 query half
    int cc2 = blk & 255;
    int c   = cc2 & (NCH - 1);
    int bh  = cc2 >> 3;
    int h = bh & (HH - 1), b = bh >> 3;
    int t = threadIdx.x, lane = t & 63, w = t >> 6;
    int u0 = qh * QH;

    // stage this half's 20 q rows
    for (int i = t; i < QH * DD; i += 256) {
        int u = i >> 6, d = i & 63;
        int lq = topi[bh * NT + u0 + u];
        qs[u][d] = Q[(((size_t)b * LL + lq) * HH + h) * DD + d];
    }

    // K row for this lane's key -> registers
    int key = c * CH + w * 64 + lane;
    const float4* kr = (const float4*)&K[(((size_t)b * LL + key) * HH + h) * DD];
    float4 kreg[16];
    #pragma unroll
    for (int j = 0; j < 16; ++j) kreg[j] = kr[j];

    // V column (d = lane) for this wave's 64 keys -> registers
    float vcol[64];
    const float* vb = &V[(((size_t)b * LL + c * CH + w * 64) * HH + h) * DD + lane];
    #pragma unroll
    for (int j = 0; j < 64; ++j) vcol[j] = vb[(size_t)j * HH * DD];

    __syncthreads();   // qs ready

    for (int uq = 0; uq < QH / 4; ++uq) {
        float o0 = 0, o1 = 0, o2 = 0, o3 = 0;
        float mv0, mv1, mv2, mv3, lv0, lv1, lv2, lv3;
        float4 ev;
        #pragma unroll
        for (int j = 0; j < 4; ++j) {
            int u = uq * 4 + j;
            const float4* q4 = (const float4*)&qs[u][0];
            float s = 0.0f;
            #pragma unroll
            for (int cc = 0; cc < 16; ++cc) {
                float4 qv = q4[cc];
                s += qv.x * kreg[cc].x + qv.y * kreg[cc].y
                   + qv.z * kreg[cc].z + qv.w * kreg[cc].w;
            }
            s *= 0.125f;   // 1/sqrt(64)
            float m = s;
            #pragma unroll
            for (int off = 32; off >= 1; off >>= 1)
                m = fmaxf(m, __shfl_xor(m, off, 64));
            float e = __expf(s - m);
            float ls = e;
            #pragma unroll
            for (int off = 32; off >= 1; off >>= 1)
                ls += __shfl_xor(ls, off, 64);
            if (j == 0) { mv0 = m; lv0 = ls; ev.x = e; }
            if (j == 1) { mv1 = m; lv1 = ls; ev.y = e; }
            if (j == 2) { mv2 = m; lv2 = ls; ev.z = e; }
            if (j == 3) { mv3 = m; lv3 = ls; ev.w = e; }
        }
        e4buf[w][lane] = ev;
        asm volatile("s_waitcnt lgkmcnt(0)" ::: "memory");   // intra-wave LDS ordering
        #pragma unroll 8
        for (int l2 = 0; l2 < 64; ++l2) {
            float4 e = e4buf[w][l2];   // broadcast read
            float  v = vcol[l2];
            o0 += e.x * v; o1 += e.y * v; o2 += e.z * v; o3 += e.w * v;
        }
        oarea[w][uq * 4 + 0][lane] = o0;
        oarea[w][uq * 4 + 1][lane] = o1;
        oarea[w][uq * 4 + 2][lane] = o2;
        oarea[w][uq * 4 + 3][lane] = o3;
        if (lane == 0) {
            mlarea[w][uq * 4 + 0][0] = mv0; mlarea[w][uq * 4 + 0][1] = lv0;
            mlarea[w][uq * 4 + 1][0] = mv1; mlarea[w][uq * 4 + 1][1] = lv1;
            mlarea[w][uq * 4 + 2][0] = mv2; mlarea[w][uq * 4 + 2][1] = lv2;
            mlarea[w][uq * 4 + 3][0] = mv3; mlarea[w][uq * 4 + 3][1] = lv3;
        }
    }
    __syncthreads();

    // combine 4 waves -> one chunk partial (for this query half)
    for (int i = t; i < QH * DD; i += 256) {
        int u = i >> 6, d = i & 63;
        float m0 = mlarea[0][u][0], m1 = mlarea[1][u][0];
        float m2 = mlarea[2][u][0], m3 = mlarea[3][u][0];
        float mb = fmaxf(fmaxf(m0, m1), fmaxf(m2, m3));
        float s0 = __expf(m0 - mb), s1 = __expf(m1 - mb);
        float s2 = __expf(m2 - mb), s3 = __expf(m3 - mb);
        float ob = oarea[0][u][d] * s0 + oarea[1][u][d] * s1
                 + oarea[2][u][d] * s2 + oarea[3][u][d] * s3;
        int gu = u0 + u;
        po[((size_t)(bh * NT + gu) * NCH + c) * DD + d] = ob;
        if (d == 0) {
            float lb = mlarea[0][u][1] * s0 + mlarea[1][u][1] * s1
                     + mlarea[2][u][1] * s2 + mlarea[3][u][1] * s3;
            pm[(bh * NT + gu) * NCH + c] = mb;
            pl[(bh * NT + gu) * NCH + c] = lb;
        }
    }
}

// ---------------------------------------------------------------------------
// Kernel 4: merge chunk partials. One wave per (bh,u), lane = d.
// ---------------------------------------------------------------------------
__global__ __launch_bounds__(256) void merge_kernel(
        const float* __restrict__ pm, const float* __restrict__ pl,
        const float* __restrict__ po, float* __restrict__ out) {
    int wid  = blockIdx.x * 4 + (threadIdx.x >> 6);
    int lane = threadIdx.x & 63;
    int u  = wid % NT;
    int bh = wid / NT;
    int h = bh & (HH - 1), b = bh >> 3;
    int base = (bh * NT + u) * NCH;

    float m = -INFINITY;
    #pragma unroll
    for (int cc = 0; cc < NCH; ++cc) m = fmaxf(m, pm[base + cc]);
    float lsum = 0.0f, o = 0.0f;
    #pragma unroll
    for (int cc = 0; cc < NCH; ++cc) {
        float sc = __expf(pm[base + cc] - m);
        lsum += pl[base + cc] * sc;
        o    += po[(size_t)(base + cc) * DD + lane] * sc;
    }
    out[(((size_t)b * NT + u) * HH + h) * DD + lane] = o / lsum;
}

extern "C" void kernel_launch(void* const* d_in, const int* in_sizes, int n_in,
                              void* d_out, int out_size, void* d_ws, size_t ws_size,
                              hipStream_t stream) {
    const float* Q   = (const float*)d_in[0];
    const float* K   = (const float*)d_in[1];
    const float* V   = (const float*)d_in[2];
    const int*   idx = (const int*)d_in[3];
    float* out = (float*)d_out;

    char* ws = (char*)d_ws;
    float* M    = (float*)ws;                         ws += (size_t)BB * HH * LL * sizeof(float);
    int*   topi = (int*)ws;                           ws += (size_t)BB * HH * NT * sizeof(int);
    float* pm   = (float*)ws;                         ws += (size_t)BB * HH * NT * NCH * sizeof(float);
    float* pl   = (float*)ws;                         ws += (size_t)BB * HH * NT * NCH * sizeof(float);
    float* po   = (float*)ws;                         // 32*40*8*64*4 = 2.62 MB

    hipLaunchKernelGGL(compute_m_kernel, dim3(BB * LL), dim3(256), 0, stream,
                       Q, K, idx, M);
    hipLaunchKernelGGL(topk_kernel, dim3(BB * HH), dim3(256), 0, stream, M, topi);
    hipLaunchKernelGGL(attn_kernel, dim3(2 * BB * HH * NCH), dim3(256), 0, stream,
                       Q, K, V, topi, pm, pl, po);
    hipLaunchKernelGGL(merge_kernel, dim3(BB * HH * NT / 4), dim3(256), 0, stream,
                       pm, pl, po, out);
}

// Round 7
// 202.835 us; speedup vs baseline: 1.1664x; 1.1664x over previous
//
#include <hip/hip_runtime.h>
#include <hip/hip_bf16.h>

// Problem constants: B=4, L=2048, H=8, D=64, SAMPLE_K=N_TOP=40
#define BB 4
#define LL 2048
#define HH 8
#define DD 64
#define SK 40
#define NT 40
#define CH 256              // keys per attn chunk
#define NCH (LL / CH)       // 8 chunks per (b,h)
#define QH 20               // queries per attn block (40 split in 2)

#define NPH 5               // compute_m phases
#define PH 8                // samples per phase
#define RS 516              // LDS row stride in dwords (2064 B): 516%32=4 -> 2-way banks (free)
#define PBUF (PH * RS)      // 4128 dwords per buffer

// ---------------------------------------------------------------------------
// Kernel 1: M[bh][l] = max_s(q . k_{idx[l,s]}) - (sum_s q . k_{idx[l,s]}) / L
// Block = (b,l), XCD-swizzled (each XCD serves one b -> K slice L2-resident).
// 5 phases x 8 samples: coalesced gather -> LDS (double-buffered, register-
// pipelined), then quarter-dot per thread (t = h*32 + s0*4 + q):
// 4 ds_read_b128 + 16 FMA + 2 quad shuffles. One 32-lane butterfly at end.
// NOTE: after the quad combine, all 4 q-lanes of a quad hold the SAME full
// dot; the 32-lane butterfly therefore sums 4 duplicate copies -> divide the
// mean term by 4 (bug found in round 6: missing /4 skewed top-k ranking).
// ---------------------------------------------------------------------------
__global__ __launch_bounds__(256) void compute_m_kernel(
        const float* __restrict__ Q, const float* __restrict__ K,
        const int* __restrict__ idx, float* __restrict__ M) {
    __shared__ float kbuf[2 * PBUF];   // 33 KB
    __shared__ int sidx[SK];

    int blk = blockIdx.x;
    int x = blk & 7, g = blk >> 3;
    int b = x >> 1;                    // XCD pair -> batch
    int l = (g << 1) | (x & 1);
    int t = threadIdx.x;

    if (t < SK) sidx[t] = idx[(size_t)l * SK + t];

    // quarter-dot mapping
    int d  = t >> 2;                   // dot id 0..63
    int q  = t & 3;                    // quarter (16 dims)
    int h  = d >> 3;                   // head 0..7
    int s0 = d & 7;                    // sample-in-phase

    // Q fragment: dims h*64 + q*16 .. +15 (16 floats in regs)
    const float4* Qb = (const float4*)(Q + ((size_t)b * LL + l) * 512 + h * 64 + q * 16);
    float4 qf0 = Qb[0], qf1 = Qb[1], qf2 = Qb[2], qf3 = Qb[3];

    const float* Kb = K + (size_t)b * LL * 512;

    // staging role: 32 lanes cover one 2-KB row; thread stages 4 float4s
    int rr = t >> 5;                   // row 0..7
    int cw = t & 31;
    __syncthreads();                   // sidx ready

    float4 st0, st1, st2, st3;
    {   // preload phase 0
        const float* src = Kb + (size_t)sidx[rr] * 512 + cw * 4;
        st0 = *(const float4*)(src);
        st1 = *(const float4*)(src + 128);
        st2 = *(const float4*)(src + 256);
        st3 = *(const float4*)(src + 384);
        float* dst = kbuf + rr * RS + cw * 4;
        *(float4*)(dst)       = st0;
        *(float4*)(dst + 128) = st1;
        *(float4*)(dst + 256) = st2;
        *(float4*)(dst + 384) = st3;
    }
    __syncthreads();

    float mx = -INFINITY, sm = 0.0f;
    #pragma unroll
    for (int p = 0; p < NPH; ++p) {
        if (p < NPH - 1) {             // issue next phase's gathers (no wait yet)
            const float* src = Kb + (size_t)sidx[(p + 1) * PH + rr] * 512 + cw * 4;
            st0 = *(const float4*)(src);
            st1 = *(const float4*)(src + 128);
            st2 = *(const float4*)(src + 256);
            st3 = *(const float4*)(src + 384);
        }
        // compute on buffer p&1 (overlaps the in-flight gathers)
        const float* kb = kbuf + (p & 1) * PBUF + s0 * RS + h * 64 + q * 16;
        float4 k0 = *(const float4*)(kb);
        float4 k1 = *(const float4*)(kb + 4);
        float4 k2 = *(const float4*)(kb + 8);
        float4 k3 = *(const float4*)(kb + 12);
        float pd = qf0.x * k0.x + qf0.y * k0.y + qf0.z * k0.z + qf0.w * k0.w
                 + qf1.x * k1.x + qf1.y * k1.y + qf1.z * k1.z + qf1.w * k1.w
                 + qf2.x * k2.x + qf2.y * k2.y + qf2.z * k2.z + qf2.w * k2.w
                 + qf3.x * k3.x + qf3.y * k3.y + qf3.z * k3.z + qf3.w * k3.w;
        pd += __shfl_xor(pd, 1, 64);   // quad combine
        pd += __shfl_xor(pd, 2, 64);
        mx = fmaxf(mx, pd);
        sm += pd;
        if (p < NPH - 1) {             // write next buffer, then make visible
            float* dst = kbuf + ((p + 1) & 1) * PBUF + rr * RS + cw * 4;
            *(float4*)(dst)       = st0;
            *(float4*)(dst + 128) = st1;
            *(float4*)(dst + 256) = st2;
            *(float4*)(dst + 384) = st3;
            __syncthreads();
        }
    }

    // final reduce over the 32 lanes of each h-group (t = h*32 + j)
    #pragma unroll
    for (int off = 16; off >= 1; off >>= 1) {
        mx = fmaxf(mx, __shfl_xor(mx, off, 64));
        sm += __shfl_xor(sm, off, 64);
    }
    if ((t & 31) == 0)
        M[((size_t)b * HH + h) * LL + l] = mx - sm * (1.0f / (4.0f * (float)LL));
}

// ---------------------------------------------------------------------------
// Kernel 2: top-40 per (b,h), lower index wins ties.
// Packed key: (ordered_float << 11) | (2047 - i). Incremental argmax.
// ---------------------------------------------------------------------------
__global__ __launch_bounds__(256) void topk_kernel(const float* __restrict__ M,
                                                   int* __restrict__ topi) {
    __shared__ unsigned long long keys[LL];   // 16 KB
    __shared__ unsigned long long wmax[4];
    __shared__ int win;
    int bh = blockIdx.x;
    int t  = threadIdx.x;
    int lane = t & 63, w = t >> 6;

    unsigned long long kmax = 0ULL;
    #pragma unroll
    for (int j = 0; j < 8; ++j) {
        int i = t + 256 * j;
        unsigned int bits = __float_as_uint(M[(size_t)bh * LL + i]);
        bits = (bits & 0x80000000u) ? ~bits : (bits | 0x80000000u);
        unsigned long long k = ((unsigned long long)bits << 11)
                             | (unsigned int)(LL - 1 - i);
        keys[i] = k;
        if (k > kmax) kmax = k;
    }
    __syncthreads();

    for (int u = 0; u < NT; ++u) {
        unsigned long long k = kmax;
        #pragma unroll
        for (int off = 32; off >= 1; off >>= 1) {
            unsigned long long o = __shfl_xor(k, off, 64);
            if (o > k) k = o;
        }
        if (lane == 0) wmax[w] = k;
        __syncthreads();
        if (t == 0) {
            unsigned long long k0 = wmax[0], k1 = wmax[1], k2 = wmax[2], k3 = wmax[3];
            if (k1 > k0) k0 = k1;
            if (k3 > k2) k2 = k3;
            if (k2 > k0) k0 = k2;
            int i = (LL - 1) - (int)(k0 & 0x7FF);
            topi[bh * NT + u] = i;
            keys[i] = 0ULL;
            win = i;
        }
        __syncthreads();
        if ((win & 255) == t) {          // only the owner rescans
            kmax = 0ULL;
            #pragma unroll
            for (int j = 0; j < 8; ++j) {
                unsigned long long kk = keys[t + 256 * j];
                if (kk > kmax) kmax = kk;
            }
        }
    }
}

// ---------------------------------------------------------------------------
// Kernel 3: flash-chunked attention, query-split for 2 waves/SIMD.
// ---------------------------------------------------------------------------
__global__ __launch_bounds__(256) void attn_kernel(
        const float* __restrict__ Q, const float* __restrict__ K,
        const float* __restrict__ V, const int* __restrict__ topi,
        float* __restrict__ pm, float* __restrict__ pl, float* __restrict__ po) {
    __shared__ float  qs[QH][DD];        //  5120 B
    __shared__ float4 e4buf[4][64];      //  4096 B
    __shared__ float  oarea[4][QH][DD];  // 20480 B
    __shared__ float  mlarea[4][QH][2];  //   640 B

    int blk = blockIdx.x;
    int qh  = blk >> 8;                  // 0/1 query half
    int cc2 = blk & 255;
    int c   = cc2 & (NCH - 1);
    int bh  = cc2 >> 3;
    int h = bh & (HH - 1), b = bh >> 3;
    int t = threadIdx.x, lane = t & 63, w = t >> 6;
    int u0 = qh * QH;

    for (int i = t; i < QH * DD; i += 256) {
        int u = i >> 6, d = i & 63;
        int lq = topi[bh * NT + u0 + u];
        qs[u][d] = Q[(((size_t)b * LL + lq) * HH + h) * DD + d];
    }

    int key = c * CH + w * 64 + lane;
    const float4* kr = (const float4*)&K[(((size_t)b * LL + key) * HH + h) * DD];
    float4 kreg[16];
    #pragma unroll
    for (int j = 0; j < 16; ++j) kreg[j] = kr[j];

    float vcol[64];
    const float* vb = &V[(((size_t)b * LL + c * CH + w * 64) * HH + h) * DD + lane];
    #pragma unroll
    for (int j = 0; j < 64; ++j) vcol[j] = vb[(size_t)j * HH * DD];

    __syncthreads();   // qs ready

    for (int uq = 0; uq < QH / 4; ++uq) {
        float o0 = 0, o1 = 0, o2 = 0, o3 = 0;
        float mv0, mv1, mv2, mv3, lv0, lv1, lv2, lv3;
        float4 ev;
        #pragma unroll
        for (int j = 0; j < 4; ++j) {
            int u = uq * 4 + j;
            const float4* q4 = (const float4*)&qs[u][0];
            float s = 0.0f;
            #pragma unroll
            for (int cc = 0; cc < 16; ++cc) {
                float4 qv = q4[cc];
                s += qv.x * kreg[cc].x + qv.y * kreg[cc].y
                   + qv.z * kreg[cc].z + qv.w * kreg[cc].w;
            }
            s *= 0.125f;   // 1/sqrt(64)
            float m = s;
            #pragma unroll
            for (int off = 32; off >= 1; off >>= 1)
                m = fmaxf(m, __shfl_xor(m, off, 64));
            float e = __expf(s - m);
            float ls = e;
            #pragma unroll
            for (int off = 32; off >= 1; off >>= 1)
                ls += __shfl_xor(ls, off, 64);
            if (j == 0) { mv0 = m; lv0 = ls; ev.x = e; }
            if (j == 1) { mv1 = m; lv1 = ls; ev.y = e; }
            if (j == 2) { mv2 = m; lv2 = ls; ev.z = e; }
            if (j == 3) { mv3 = m; lv3 = ls; ev.w = e; }
        }
        e4buf[w][lane] = ev;
        asm volatile("s_waitcnt lgkmcnt(0)" ::: "memory");
        #pragma unroll 8
        for (int l2 = 0; l2 < 64; ++l2) {
            float4 e = e4buf[w][l2];
            float  v = vcol[l2];
            o0 += e.x * v; o1 += e.y * v; o2 += e.z * v; o3 += e.w * v;
        }
        oarea[w][uq * 4 + 0][lane] = o0;
        oarea[w][uq * 4 + 1][lane] = o1;
        oarea[w][uq * 4 + 2][lane] = o2;
        oarea[w][uq * 4 + 3][lane] = o3;
        if (lane == 0) {
            mlarea[w][uq * 4 + 0][0] = mv0; mlarea[w][uq * 4 + 0][1] = lv0;
            mlarea[w][uq * 4 + 1][0] = mv1; mlarea[w][uq * 4 + 1][1] = lv1;
            mlarea[w][uq * 4 + 2][0] = mv2; mlarea[w][uq * 4 + 2][1] = lv2;
            mlarea[w][uq * 4 + 3][0] = mv3; mlarea[w][uq * 4 + 3][1] = lv3;
        }
    }
    __syncthreads();

    for (int i = t; i < QH * DD; i += 256) {
        int u = i >> 6, d = i & 63;
        float m0 = mlarea[0][u][0], m1 = mlarea[1][u][0];
        float m2 = mlarea[2][u][0], m3 = mlarea[3][u][0];
        float mb = fmaxf(fmaxf(m0, m1), fmaxf(m2, m3));
        float s0 = __expf(m0 - mb), s1 = __expf(m1 - mb);
        float s2 = __expf(m2 - mb), s3 = __expf(m3 - mb);
        float ob = oarea[0][u][d] * s0 + oarea[1][u][d] * s1
                 + oarea[2][u][d] * s2 + oarea[3][u][d] * s3;
        int gu = u0 + u;
        po[((size_t)(bh * NT + gu) * NCH + c) * DD + d] = ob;
        if (d == 0) {
            float lb = mlarea[0][u][1] * s0 + mlarea[1][u][1] * s1
                     + mlarea[2][u][1] * s2 + mlarea[3][u][1] * s3;
            pm[(bh * NT + gu) * NCH + c] = mb;
            pl[(bh * NT + gu) * NCH + c] = lb;
        }
    }
}

// ---------------------------------------------------------------------------
// Kernel 4: merge chunk partials. One wave per (bh,u), lane = d.
// ---------------------------------------------------------------------------
__global__ __launch_bounds__(256) void merge_kernel(
        const float* __restrict__ pm, const float* __restrict__ pl,
        const float* __restrict__ po, float* __restrict__ out) {
    int wid  = blockIdx.x * 4 + (threadIdx.x >> 6);
    int lane = threadIdx.x & 63;
    int u  = wid % NT;
    int bh = wid / NT;
    int h = bh & (HH - 1), b = bh >> 3;
    int base = (bh * NT + u) * NCH;

    float m = -INFINITY;
    #pragma unroll
    for (int cc = 0; cc < NCH; ++cc) m = fmaxf(m, pm[base + cc]);
    float lsum = 0.0f, o = 0.0f;
    #pragma unroll
    for (int cc = 0; cc < NCH; ++cc) {
        float sc = __expf(pm[base + cc] - m);
        lsum += pl[base + cc] * sc;
        o    += po[(size_t)(base + cc) * DD + lane] * sc;
    }
    out[(((size_t)b * NT + u) * HH + h) * DD + lane] = o / lsum;
}

extern "C" void kernel_launch(void* const* d_in, const int* in_sizes, int n_in,
                              void* d_out, int out_size, void* d_ws, size_t ws_size,
                              hipStream_t stream) {
    const float* Q   = (const float*)d_in[0];
    const float* K   = (const float*)d_in[1];
    const float* V   = (const float*)d_in[2];
    const int*   idx = (const int*)d_in[3];
    float* out = (float*)d_out;

    char* ws = (char*)d_ws;
    float* M    = (float*)ws;                         ws += (size_t)BB * HH * LL * sizeof(float);
    int*   topi = (int*)ws;                           ws += (size_t)BB * HH * NT * sizeof(int);
    float* pm   = (float*)ws;                         ws += (size_t)BB * HH * NT * NCH * sizeof(float);
    float* pl   = (float*)ws;                         ws += (size_t)BB * HH * NT * NCH * sizeof(float);
    float* po   = (float*)ws;                         // 2.62 MB

    hipLaunchKernelGGL(compute_m_kernel, dim3(BB * LL), dim3(256), 0, stream,
                       Q, K, idx, M);
    hipLaunchKernelGGL(topk_kernel, dim3(BB * HH), dim3(256), 0, stream, M, topi);
    hipLaunchKernelGGL(attn_kernel, dim3(2 * BB * HH * NCH), dim3(256), 0, stream,
                       Q, K, V, topi, pm, pl, po);
    hipLaunchKernelGGL(merge_kernel, dim3(BB * HH * NT / 4), dim3(256), 0, stream,
                       pm, pl, po, out);
}

// Round 8
// 174.000 us; speedup vs baseline: 1.3597x; 1.1657x over previous
//
#include <hip/hip_runtime.h>
#include <hip/hip_bf16.h>

// Problem constants: B=4, L=2048, H=8, D=64, SAMPLE_K=N_TOP=40
#define BB 4
#define LL 2048
#define HH 8
#define DD 64
#define SK 40
#define NT 40
#define CH 256              // keys per attn chunk
#define NCH (LL / CH)       // 8 chunks per (b,h)
#define QH 20               // queries per attn block (40 split in 2)

#define NPH 5               // compute_m phases
#define PH 8                // samples per phase
#define RS 516              // LDS row stride in dwords: 516%32=4 -> 2-way banks (free)
#define PBUF (PH * RS)      // 4128 dwords per buffer

// ---------------------------------------------------------------------------
// Kernel 1: M[bh][l] = max_s(q . k_{idx[l,s]}) - (sum_s q . k_{idx[l,s]}) / L
// Block = (b,l), XCD-swizzled; 5 phases x 8 samples, LDS double-buffered;
// quarter-dot per thread. Mean term /4: quad lanes hold duplicate dots.
// ---------------------------------------------------------------------------
__global__ __launch_bounds__(256) void compute_m_kernel(
        const float* __restrict__ Q, const float* __restrict__ K,
        const int* __restrict__ idx, float* __restrict__ M) {
    __shared__ float kbuf[2 * PBUF];   // 33 KB
    __shared__ int sidx[SK];

    int blk = blockIdx.x;
    int x = blk & 7, g = blk >> 3;
    int b = x >> 1;                    // XCD pair -> batch
    int l = (g << 1) | (x & 1);
    int t = threadIdx.x;

    if (t < SK) sidx[t] = idx[(size_t)l * SK + t];

    int d  = t >> 2;                   // dot id 0..63
    int q  = t & 3;                    // quarter (16 dims)
    int h  = d >> 3;                   // head 0..7
    int s0 = d & 7;                    // sample-in-phase

    const float4* Qb = (const float4*)(Q + ((size_t)b * LL + l) * 512 + h * 64 + q * 16);
    float4 qf0 = Qb[0], qf1 = Qb[1], qf2 = Qb[2], qf3 = Qb[3];

    const float* Kb = K + (size_t)b * LL * 512;

    int rr = t >> 5;                   // staging row 0..7
    int cw = t & 31;
    __syncthreads();                   // sidx ready

    float4 st0, st1, st2, st3;
    {   // preload phase 0
        const float* src = Kb + (size_t)sidx[rr] * 512 + cw * 4;
        st0 = *(const float4*)(src);
        st1 = *(const float4*)(src + 128);
        st2 = *(const float4*)(src + 256);
        st3 = *(const float4*)(src + 384);
        float* dst = kbuf + rr * RS + cw * 4;
        *(float4*)(dst)       = st0;
        *(float4*)(dst + 128) = st1;
        *(float4*)(dst + 256) = st2;
        *(float4*)(dst + 384) = st3;
    }
    __syncthreads();

    float mx = -INFINITY, sm = 0.0f;
    #pragma unroll
    for (int p = 0; p < NPH; ++p) {
        if (p < NPH - 1) {             // issue next phase's gathers
            const float* src = Kb + (size_t)sidx[(p + 1) * PH + rr] * 512 + cw * 4;
            st0 = *(const float4*)(src);
            st1 = *(const float4*)(src + 128);
            st2 = *(const float4*)(src + 256);
            st3 = *(const float4*)(src + 384);
        }
        const float* kb = kbuf + (p & 1) * PBUF + s0 * RS + h * 64 + q * 16;
        float4 k0 = *(const float4*)(kb);
        float4 k1 = *(const float4*)(kb + 4);
        float4 k2 = *(const float4*)(kb + 8);
        float4 k3 = *(const float4*)(kb + 12);
        float pd = qf0.x * k0.x + qf0.y * k0.y + qf0.z * k0.z + qf0.w * k0.w
                 + qf1.x * k1.x + qf1.y * k1.y + qf1.z * k1.z + qf1.w * k1.w
                 + qf2.x * k2.x + qf2.y * k2.y + qf2.z * k2.z + qf2.w * k2.w
                 + qf3.x * k3.x + qf3.y * k3.y + qf3.z * k3.z + qf3.w * k3.w;
        pd += __shfl_xor(pd, 1, 64);   // quad combine
        pd += __shfl_xor(pd, 2, 64);
        mx = fmaxf(mx, pd);
        sm += pd;
        if (p < NPH - 1) {
            float* dst = kbuf + ((p + 1) & 1) * PBUF + rr * RS + cw * 4;
            *(float4*)(dst)       = st0;
            *(float4*)(dst + 128) = st1;
            *(float4*)(dst + 256) = st2;
            *(float4*)(dst + 384) = st3;
            __syncthreads();
        }
    }

    #pragma unroll
    for (int off = 16; off >= 1; off >>= 1) {
        mx = fmaxf(mx, __shfl_xor(mx, off, 64));
        sm += __shfl_xor(sm, off, 64);
    }
    if ((t & 31) == 0)
        M[((size_t)b * HH + h) * LL + l] = mx - sm * (1.0f / (4.0f * (float)LL));
}

// ---------------------------------------------------------------------------
// Kernel 2: top-40 per (b,h), lower index wins ties. Incremental argmax.
// ---------------------------------------------------------------------------
__global__ __launch_bounds__(256) void topk_kernel(const float* __restrict__ M,
                                                   int* __restrict__ topi) {
    __shared__ unsigned long long keys[LL];   // 16 KB
    __shared__ unsigned long long wmax[4];
    __shared__ int win;
    int bh = blockIdx.x;
    int t  = threadIdx.x;
    int lane = t & 63, w = t >> 6;

    unsigned long long kmax = 0ULL;
    #pragma unroll
    for (int j = 0; j < 8; ++j) {
        int i = t + 256 * j;
        unsigned int bits = __float_as_uint(M[(size_t)bh * LL + i]);
        bits = (bits & 0x80000000u) ? ~bits : (bits | 0x80000000u);
        unsigned long long k = ((unsigned long long)bits << 11)
                             | (unsigned int)(LL - 1 - i);
        keys[i] = k;
        if (k > kmax) kmax = k;
    }
    __syncthreads();

    for (int u = 0; u < NT; ++u) {
        unsigned long long k = kmax;
        #pragma unroll
        for (int off = 32; off >= 1; off >>= 1) {
            unsigned long long o = __shfl_xor(k, off, 64);
            if (o > k) k = o;
        }
        if (lane == 0) wmax[w] = k;
        __syncthreads();
        if (t == 0) {
            unsigned long long k0 = wmax[0], k1 = wmax[1], k2 = wmax[2], k3 = wmax[3];
            if (k1 > k0) k0 = k1;
            if (k3 > k2) k2 = k3;
            if (k2 > k0) k0 = k2;
            int i = (LL - 1) - (int)(k0 & 0x7FF);
            topi[bh * NT + u] = i;
            keys[i] = 0ULL;
            win = i;
        }
        __syncthreads();
        if ((win & 255) == t) {          // only the owner rescans
            kmax = 0ULL;
            #pragma unroll
            for (int j = 0; j < 8; ++j) {
                unsigned long long kk = keys[t + 256 * j];
                if (kk > kmax) kmax = kk;
            }
        }
    }
}

// ---------------------------------------------------------------------------
// Kernel 3: flash-chunked attention, query-split.
// __launch_bounds__(256,3): VGPR cap ~170 so kreg[16]x4 + vcol[64] stay in
// registers (round 7: default heuristic capped at 60 VGPR -> spilled both to
// scratch, 36 MB HBM writes). PV loop FULLY unrolled -> static vcol indices.
// ---------------------------------------------------------------------------
__global__ __launch_bounds__(256, 3) void attn_kernel(
        const float* __restrict__ Q, const float* __restrict__ K,
        const float* __restrict__ V, const int* __restrict__ topi,
        float* __restrict__ pm, float* __restrict__ pl, float* __restrict__ po) {
    __shared__ float  qs[QH][DD];        //  5120 B
    __shared__ float4 e4buf[4][64];      //  4096 B
    __shared__ float  oarea[4][QH][DD];  // 20480 B
    __shared__ float  mlarea[4][QH][2];  //   640 B

    int blk = blockIdx.x;
    int qh  = blk >> 8;                  // 0/1 query half
    int cc2 = blk & 255;
    int c   = cc2 & (NCH - 1);
    int bh  = cc2 >> 3;
    int h = bh & (HH - 1), b = bh >> 3;
    int t = threadIdx.x, lane = t & 63, w = t >> 6;
    int u0 = qh * QH;

    for (int i = t; i < QH * DD; i += 256) {
        int u = i >> 6, d = i & 63;
        int lq = topi[bh * NT + u0 + u];
        qs[u][d] = Q[(((size_t)b * LL + lq) * HH + h) * DD + d];
    }

    int key = c * CH + w * 64 + lane;
    const float4* kr = (const float4*)&K[(((size_t)b * LL + key) * HH + h) * DD];
    float4 kreg[16];
    #pragma unroll
    for (int j = 0; j < 16; ++j) kreg[j] = kr[j];

    float vcol[64];
    const float* vb = &V[(((size_t)b * LL + c * CH + w * 64) * HH + h) * DD + lane];
    #pragma unroll
    for (int j = 0; j < 64; ++j) vcol[j] = vb[(size_t)j * HH * DD];

    __syncthreads();   // qs ready

    for (int uq = 0; uq < QH / 4; ++uq) {
        float o0 = 0, o1 = 0, o2 = 0, o3 = 0;
        float mv0, mv1, mv2, mv3, lv0, lv1, lv2, lv3;
        float4 ev;
        #pragma unroll
        for (int j = 0; j < 4; ++j) {
            int u = uq * 4 + j;
            const float4* q4 = (const float4*)&qs[u][0];
            float s = 0.0f;
            #pragma unroll
            for (int cc = 0; cc < 16; ++cc) {
                float4 qv = q4[cc];
                s += qv.x * kreg[cc].x + qv.y * kreg[cc].y
                   + qv.z * kreg[cc].z + qv.w * kreg[cc].w;
            }
            s *= 0.125f;   // 1/sqrt(64)
            float m = s;
            #pragma unroll
            for (int off = 32; off >= 1; off >>= 1)
                m = fmaxf(m, __shfl_xor(m, off, 64));
            float e = __expf(s - m);
            float ls = e;
            #pragma unroll
            for (int off = 32; off >= 1; off >>= 1)
                ls += __shfl_xor(ls, off, 64);
            if (j == 0) { mv0 = m; lv0 = ls; ev.x = e; }
            if (j == 1) { mv1 = m; lv1 = ls; ev.y = e; }
            if (j == 2) { mv2 = m; lv2 = ls; ev.z = e; }
            if (j == 3) { mv3 = m; lv3 = ls; ev.w = e; }
        }
        e4buf[w][lane] = ev;
        asm volatile("s_waitcnt lgkmcnt(0)" ::: "memory");
        #pragma unroll
        for (int l2 = 0; l2 < 64; ++l2) {      // FULL unroll: vcol static
            float4 e = e4buf[w][l2];
            float  v = vcol[l2];
            o0 += e.x * v; o1 += e.y * v; o2 += e.z * v; o3 += e.w * v;
        }
        oarea[w][uq * 4 + 0][lane] = o0;
        oarea[w][uq * 4 + 1][lane] = o1;
        oarea[w][uq * 4 + 2][lane] = o2;
        oarea[w][uq * 4 + 3][lane] = o3;
        if (lane == 0) {
            mlarea[w][uq * 4 + 0][0] = mv0; mlarea[w][uq * 4 + 0][1] = lv0;
            mlarea[w][uq * 4 + 1][0] = mv1; mlarea[w][uq * 4 + 1][1] = lv1;
            mlarea[w][uq * 4 + 2][0] = mv2; mlarea[w][uq * 4 + 2][1] = lv2;
            mlarea[w][uq * 4 + 3][0] = mv3; mlarea[w][uq * 4 + 3][1] = lv3;
        }
    }
    __syncthreads();

    for (int i = t; i < QH * DD; i += 256) {
        int u = i >> 6, d = i & 63;
        float m0 = mlarea[0][u][0], m1 = mlarea[1][u][0];
        float m2 = mlarea[2][u][0], m3 = mlarea[3][u][0];
        float mb = fmaxf(fmaxf(m0, m1), fmaxf(m2, m3));
        float s0 = __expf(m0 - mb), s1 = __expf(m1 - mb);
        float s2 = __expf(m2 - mb), s3 = __expf(m3 - mb);
        float ob = oarea[0][u][d] * s0 + oarea[1][u][d] * s1
                 + oarea[2][u][d] * s2 + oarea[3][u][d] * s3;
        int gu = u0 + u;
        po[((size_t)(bh * NT + gu) * NCH + c) * DD + d] = ob;
        if (d == 0) {
            float lb = mlarea[0][u][1] * s0 + mlarea[1][u][1] * s1
                     + mlarea[2][u][1] * s2 + mlarea[3][u][1] * s3;
            pm[(bh * NT + gu) * NCH + c] = mb;
            pl[(bh * NT + gu) * NCH + c] = lb;
        }
    }
}

// ---------------------------------------------------------------------------
// Kernel 4: merge chunk partials. One wave per (bh,u), lane = d.
// ---------------------------------------------------------------------------
__global__ __launch_bounds__(256) void merge_kernel(
        const float* __restrict__ pm, const float* __restrict__ pl,
        const float* __restrict__ po, float* __restrict__ out) {
    int wid  = blockIdx.x * 4 + (threadIdx.x >> 6);
    int lane = threadIdx.x & 63;
    int u  = wid % NT;
    int bh = wid / NT;
    int h = bh & (HH - 1), b = bh >> 3;
    int base = (bh * NT + u) * NCH;

    float m = -INFINITY;
    #pragma unroll
    for (int cc = 0; cc < NCH; ++cc) m = fmaxf(m, pm[base + cc]);
    float lsum = 0.0f, o = 0.0f;
    #pragma unroll
    for (int cc = 0; cc < NCH; ++cc) {
        float sc = __expf(pm[base + cc] - m);
        lsum += pl[base + cc] * sc;
        o    += po[(size_t)(base + cc) * DD + lane] * sc;
    }
    out[(((size_t)b * NT + u) * HH + h) * DD + lane] = o / lsum;
}

extern "C" void kernel_launch(void* const* d_in, const int* in_sizes, int n_in,
                              void* d_out, int out_size, void* d_ws, size_t ws_size,
                              hipStream_t stream) {
    const float* Q   = (const float*)d_in[0];
    const float* K   = (const float*)d_in[1];
    const float* V   = (const float*)d_in[2];
    const int*   idx = (const int*)d_in[3];
    float* out = (float*)d_out;

    char* ws = (char*)d_ws;
    float* M    = (float*)ws;                         ws += (size_t)BB * HH * LL * sizeof(float);
    int*   topi = (int*)ws;                           ws += (size_t)BB * HH * NT * sizeof(int);
    float* pm   = (float*)ws;                         ws += (size_t)BB * HH * NT * NCH * sizeof(float);
    float* pl   = (float*)ws;                         ws += (size_t)BB * HH * NT * NCH * sizeof(float);
    float* po   = (float*)ws;                         // 2.62 MB

    hipLaunchKernelGGL(compute_m_kernel, dim3(BB * LL), dim3(256), 0, stream,
                       Q, K, idx, M);
    hipLaunchKernelGGL(topk_kernel, dim3(BB * HH), dim3(256), 0, stream, M, topi);
    hipLaunchKernelGGL(attn_kernel, dim3(2 * BB * HH * NCH), dim3(256), 0, stream,
                       Q, K, V, topi, pm, pl, po);
    hipLaunchKernelGGL(merge_kernel, dim3(BB * HH * NT / 4), dim3(256), 0, stream,
                       pm, pl, po, out);
}